// Round 10
// baseline (219.842 us; speedup 1.0000x reference)
//
#include <hip/hip_runtime.h>
#include <stdint.h>

#define FDIM 256
#define KDIM 1024   // 4*F : [x | h | Tx1 | L^Tx1]

typedef __attribute__((ext_vector_type(8))) short short8;
typedef __attribute__((ext_vector_type(4))) float floatx4;

#define GLOBAL_AS __attribute__((address_space(1)))
#define LDS_AS    __attribute__((address_space(3)))

static __device__ __forceinline__ unsigned short f2bf(float f) {
    unsigned int u = __float_as_uint(f);
    unsigned int r = (u + 0x7FFFu + ((u >> 16) & 1u)) >> 16;
    return (unsigned short)r;
}
static __device__ __forceinline__ float bf2f(unsigned short s) {
    return __uint_as_float(((unsigned int)s) << 16);
}
static __device__ __forceinline__ float sig(float x) {
    return 1.f / (1.f + __expf(-x));
}

// ---------------- fused prep: packBt + packA + degree/count ----------------
// Blocks [0, nbB): gate-interleaved packed B^T with Chebyshev fold:
//   out = x@W + h@(Th0-Th2) + Tx1@Th1 + (L^Tx1)@(2*Th2)
// Blocks [nbB, ...): bf16-pack x|h into A (32 thr/node, 16B stores) + edge atomics.
__global__ void k_pre(const float* __restrict__ x, const float* __restrict__ h,
                      unsigned short* __restrict__ A, int n,
                      const int* __restrict__ src, const int* __restrict__ dst,
                      const float* __restrict__ ew, float* deg, int* cnt,
                      const float* __restrict__ W, const float* __restrict__ theta,
                      unsigned short* __restrict__ Bt, int e, int nbB) {
    int bid = blockIdx.x;
    if (bid < nbB) {
        int t = bid * 256 + (int)threadIdx.x;       // over KDIM*KDIM
        int p = t >> 10, r = t & 1023;
        int group = p >> 6, gate = (p >> 4) & 3;
        int feat = (group << 4) | (p & 15);
        int kb = r >> 8, rr = r & 255;
        size_t g3 = (size_t)(gate * 3);
        float v;
        if (kb == 0)      v = W[((size_t)(gate * FDIM + rr)) * FDIM + feat];
        else if (kb == 1) v = theta[((g3 + 0) * FDIM + rr) * FDIM + feat]
                            - theta[((g3 + 2) * FDIM + rr) * FDIM + feat];
        else if (kb == 2) v = theta[((g3 + 1) * FDIM + rr) * FDIM + feat];
        else              v = 2.f * theta[((g3 + 2) * FDIM + rr) * FDIM + feat];
        Bt[t] = f2bf(v);
        return;
    }
    int t = (bid - nbB) * 256 + (int)threadIdx.x;
    if (t < e) {
        atomicAdd(&deg[src[t]], ew[t]);
        atomicAdd(&cnt[dst[t]], 1);
    }
    int node = t >> 5, q = t & 31;
    if (node >= n) return;
    const float* xp = x + (size_t)node * FDIM + q * 8;
    const float* hp = h + (size_t)node * FDIM + q * 8;
    floatx4 x0 = *(const floatx4*)xp, x1 = *(const floatx4*)(xp + 4);
    floatx4 h0 = *(const floatx4*)hp, h1 = *(const floatx4*)(hp + 4);
    short8 ox, oh;
#pragma unroll
    for (int k = 0; k < 4; ++k) {
        ox[k] = (short)f2bf(x0[k]); ox[4 + k] = (short)f2bf(x1[k]);
        oh[k] = (short)f2bf(h0[k]); oh[4 + k] = (short)f2bf(h1[k]);
    }
    *(short8*)(A + (size_t)node * KDIM + q * 8) = ox;
    *(short8*)(A + (size_t)node * KDIM + FDIM + q * 8) = oh;
}

// hierarchical scan, stage 1: per-1024-block inclusive scan -> offs[i+1], block total -> part[b]
__launch_bounds__(1024)
__global__ void k_scan1(const int* __restrict__ cnt, int* __restrict__ offs,
                        int* __restrict__ part, int n) {
    __shared__ int wsum[16];
    int b = blockIdx.x;
    int i = b * 1024 + (int)threadIdx.x;
    int lane = threadIdx.x & 63;
    int wid = threadIdx.x >> 6;
    int x = (i < n) ? cnt[i] : 0;
#pragma unroll
    for (int s = 1; s < 64; s <<= 1) {
        int t = __shfl_up(x, s);
        if (lane >= s) x += t;
    }
    if (lane == 63) wsum[wid] = x;
    __syncthreads();
    if (wid == 0) {
        int y = (lane < 16) ? wsum[lane] : 0;
#pragma unroll
        for (int s = 1; s < 16; s <<= 1) {
            int t = __shfl_up(y, s);
            if (lane >= s) y += t;
        }
        if (lane < 16) wsum[lane] = y;
    }
    __syncthreads();
    int wbase = (wid > 0) ? wsum[wid - 1] : 0;
    if (i < n) offs[i + 1] = wbase + x;
    if (threadIdx.x == 1023) part[b] = wsum[15];
}

// stage 2: add exclusive prefix of part[] to each block's region (nb <= 64)
__launch_bounds__(1024)
__global__ void k_scan2(int* __restrict__ offs, const int* __restrict__ part, int n) {
    __shared__ int sprefix;
    int b = blockIdx.x;
    if (threadIdx.x < 64) {
        int p = ((int)threadIdx.x < b) ? part[threadIdx.x] : 0;
#pragma unroll
        for (int s = 32; s; s >>= 1) p += __shfl_down(p, s);
        if (threadIdx.x == 0) sprefix = p;
    }
    __syncthreads();
    int i = b * 1024 + (int)threadIdx.x;
    if (i < n) offs[i + 1] += sprefix;
    if (b == 0 && threadIdx.x == 0) offs[0] = 0;
}

// scatter with inline rsqrt normalization; CSR record packed as int2{src, w}
__global__ void k_scatter(const int* __restrict__ src, const int* __restrict__ dst,
                          const float* __restrict__ ew, const float* __restrict__ deg,
                          const int* __restrict__ offs, int* cur,
                          int2* __restrict__ csr, int e) {
    int i = blockIdx.x * blockDim.x + threadIdx.x;
    if (i < e) {
        int s = src[i], d = dst[i];
        float ds_ = deg[s], dd = deg[d];
        float rs = ds_ > 0.f ? rsqrtf(fmaxf(ds_, 1e-12f)) : 0.f;
        float rd = dd > 0.f ? rsqrtf(fmaxf(dd, 1e-12f)) : 0.f;
        float wn = -rs * ew[i] * rd;
        int pos = offs[d] + atomicAdd(&cur[d], 1);
        csr[pos] = make_int2(s, __float_as_int(wn));
    }
}

// ---------------- sparse prop (CSR gather, wave per node, 2 half-waves x 4 unroll) ----------------

// Tx1 = prop(h): gather bf16 h from A[:,256:512], write bf16 to A[:,512:768]
__launch_bounds__(256)
__global__ void k_prop1(unsigned short* __restrict__ A, const int* __restrict__ offs,
                        const int2* __restrict__ csr, int n) {
    int wid = (blockIdx.x * blockDim.x + threadIdx.x) >> 6;
    int lane = threadIdx.x & 63;
    if (wid >= n) return;
    int half = lane >> 5, l = lane & 31;
    int beg = offs[wid], end = offs[wid + 1];
    float a[8] = {0.f, 0.f, 0.f, 0.f, 0.f, 0.f, 0.f, 0.f};
    int j = beg + half;
    for (; j + 6 < end; j += 8) {
        int2 e0 = csr[j], e1 = csr[j + 2], e2 = csr[j + 4], e3 = csr[j + 6];
        short8 v0 = *(const short8*)(A + (size_t)e0.x * KDIM + FDIM + l * 8);
        short8 v1 = *(const short8*)(A + (size_t)e1.x * KDIM + FDIM + l * 8);
        short8 v2 = *(const short8*)(A + (size_t)e2.x * KDIM + FDIM + l * 8);
        short8 v3 = *(const short8*)(A + (size_t)e3.x * KDIM + FDIM + l * 8);
        float w0 = __int_as_float(e0.y), w1 = __int_as_float(e1.y);
        float w2 = __int_as_float(e2.y), w3 = __int_as_float(e3.y);
#pragma unroll
        for (int k = 0; k < 8; ++k)
            a[k] += w0 * bf2f((unsigned short)v0[k]) + w1 * bf2f((unsigned short)v1[k])
                  + w2 * bf2f((unsigned short)v2[k]) + w3 * bf2f((unsigned short)v3[k]);
    }
    for (; j < end; j += 2) {
        int2 e0 = csr[j];
        float w0 = __int_as_float(e0.y);
        short8 v0 = *(const short8*)(A + (size_t)e0.x * KDIM + FDIM + l * 8);
#pragma unroll
        for (int k = 0; k < 8; ++k) a[k] += w0 * bf2f((unsigned short)v0[k]);
    }
#pragma unroll
    for (int k = 0; k < 8; ++k) a[k] += __shfl_xor(a[k], 32);
    if (half == 0) {
        short8 o;
#pragma unroll
        for (int k = 0; k < 8; ++k) o[k] = (short)f2bf(a[k]);
        *(short8*)(A + (size_t)wid * KDIM + 2 * FDIM + l * 8) = o;
    }
}

// T2' = L^(Tx1): pure gather of Tx1 (Cheb fold moved the -h / x2 into Bt)
__launch_bounds__(256)
__global__ void k_prop2(unsigned short* __restrict__ A, const int* __restrict__ offs,
                        const int2* __restrict__ csr, int n) {
    int wid = (blockIdx.x * blockDim.x + threadIdx.x) >> 6;
    int lane = threadIdx.x & 63;
    if (wid >= n) return;
    int half = lane >> 5, l = lane & 31;
    int beg = offs[wid], end = offs[wid + 1];
    float a[8] = {0.f, 0.f, 0.f, 0.f, 0.f, 0.f, 0.f, 0.f};
    int j = beg + half;
    for (; j + 6 < end; j += 8) {
        int2 e0 = csr[j], e1 = csr[j + 2], e2 = csr[j + 4], e3 = csr[j + 6];
        short8 v0 = *(const short8*)(A + (size_t)e0.x * KDIM + 2 * FDIM + l * 8);
        short8 v1 = *(const short8*)(A + (size_t)e1.x * KDIM + 2 * FDIM + l * 8);
        short8 v2 = *(const short8*)(A + (size_t)e2.x * KDIM + 2 * FDIM + l * 8);
        short8 v3 = *(const short8*)(A + (size_t)e3.x * KDIM + 2 * FDIM + l * 8);
        float w0 = __int_as_float(e0.y), w1 = __int_as_float(e1.y);
        float w2 = __int_as_float(e2.y), w3 = __int_as_float(e3.y);
#pragma unroll
        for (int k = 0; k < 8; ++k)
            a[k] += w0 * bf2f((unsigned short)v0[k]) + w1 * bf2f((unsigned short)v1[k])
                  + w2 * bf2f((unsigned short)v2[k]) + w3 * bf2f((unsigned short)v3[k]);
    }
    for (; j < end; j += 2) {
        int2 e0 = csr[j];
        float w0 = __int_as_float(e0.y);
        short8 v0 = *(const short8*)(A + (size_t)e0.x * KDIM + 2 * FDIM + l * 8);
#pragma unroll
        for (int k = 0; k < 8; ++k) a[k] += w0 * bf2f((unsigned short)v0[k]);
    }
#pragma unroll
    for (int k = 0; k < 8; ++k) a[k] += __shfl_xor(a[k], 32);
    if (half == 0) {
        short8 o;
#pragma unroll
        for (int k = 0; k < 8; ++k) o[k] = (short)f2bf(a[k]);
        *(short8*)(A + (size_t)wid * KDIM + 3 * FDIM + l * 8) = o;
    }
}

// ---------------- GEMM + fused LSTM epilogue ----------------
// T3 "minimum 2-phase" in PLAIN HIP (catalog recipe): double-buffered LDS,
// STAGE(kt+1) issued BEFORE compute of kt, ONE __syncthreads per K-iter
// (its implicit vmcnt(0)+lgkmcnt(0) drain is the per-tile wait; no inline asm,
// no sched_barrier pins — those regressed in R4/m141). Staging latency of
// tile kt+1 overlaps the 32-MFMA compute of tile kt.
// BK=64, XOR-swizzled LDS (linear dest + inverse-swizzled source, rule #21).
// __launch_bounds__(256,3): 170-VGPR budget, no spills ((256,5) spilled, R7).

__launch_bounds__(256, 3)
__global__ void k_gemm(const unsigned short* __restrict__ A, const unsigned short* __restrict__ Bt,
                       const float* __restrict__ c, const float* __restrict__ b_conv,
                       const float* __restrict__ b, const float* __restrict__ w_c,
                       const float* __restrict__ Wcls, const float* __restrict__ bcls,
                       float* __restrict__ out_h, float* __restrict__ out_c,
                       float* __restrict__ out_cls, int M, int mtiles) {
    __shared__ unsigned short sA[2][128 * 64];
    __shared__ unsigned short sB[2][128 * 64];
    int tid = threadIdx.x;
    int lane = tid & 63;
    int w = tid >> 6;
    // XCD-aware swizzle: 8 consecutive nt-blocks (one A panel) land on one XCD chunk
    int nb = mtiles * 8;
    int bid = blockIdx.x;
    int wg = (bid & 7) * (nb >> 3) + (bid >> 3);
    int mt = wg >> 3;
    int nt = wg & 7;
    int brow = mt * 128, bcol = nt * 128;
    int wr = (w >> 1) * 64, wc = (w & 1) * 64;
    int l15 = lane & 15, l4 = lane >> 4;

    auto STAGE = [&](int kt, int bufi) {
        int k0 = kt * 64;
#pragma unroll
        for (int p = 0; p < 4; ++p) {
            int cch = tid + p * 256;            // 0..1023 chunks of 16B
            int row = cch >> 3, cslot = cch & 7;
            int csrc = cslot ^ (row & 7);       // inverse-swizzled source chunk
            const unsigned short* g = A + (size_t)(brow + row) * KDIM + k0 + csrc * 8;
            __builtin_amdgcn_global_load_lds((const GLOBAL_AS void*)g,
                                             (LDS_AS void*)(sA[bufi] + cch * 8), 16, 0, 0);
        }
#pragma unroll
        for (int p = 0; p < 4; ++p) {
            int cch = tid + p * 256;
            int row = cch >> 3, cslot = cch & 7;
            int csrc = cslot ^ (row & 7);
            const unsigned short* g = Bt + (size_t)(bcol + row) * KDIM + k0 + csrc * 8;
            __builtin_amdgcn_global_load_lds((const GLOBAL_AS void*)g,
                                             (LDS_AS void*)(sB[bufi] + cch * 8), 16, 0, 0);
        }
    };

    floatx4 acc[4][4];
#pragma unroll
    for (int m = 0; m < 4; ++m)
#pragma unroll
        for (int g = 0; g < 4; ++g)
            acc[m][g] = (floatx4){0.f, 0.f, 0.f, 0.f};

    STAGE(0, 0);
    __syncthreads();                        // drain prologue staging

    for (int kt = 0; kt < 16; ++kt) {
        int cur = kt & 1;
        if (kt < 15) STAGE(kt + 1, cur ^ 1);   // issue next-tile loads FIRST

#pragma unroll
        for (int ks = 0; ks < 2; ++ks) {
            short8 af[4], bfr[4];
#pragma unroll
            for (int m = 0; m < 4; ++m) {
                int ra = wr + m * 16 + l15;
                af[m] = *(const short8*)(sA[cur] + ra * 64 + ((ks * 4 + l4) ^ (ra & 7)) * 8);
            }
#pragma unroll
            for (int g = 0; g < 4; ++g) {
                int rb = wc + g * 16 + l15;
                bfr[g] = *(const short8*)(sB[cur] + rb * 64 + ((ks * 4 + l4) ^ (rb & 7)) * 8);
            }
#pragma unroll
            for (int m = 0; m < 4; ++m)
#pragma unroll
                for (int g = 0; g < 4; ++g)
                    acc[m][g] = __builtin_amdgcn_mfma_f32_16x16x32_bf16(af[m], bfr[g], acc[m][g], 0, 0, 0);
        }
        // single barrier: drains this wave's prefetch (vmcnt0) and publishes all
        // waves' LDS writes; ds_reads above are register-complete (lgkmcnt0)
        __syncthreads();
    }

    // fused epilogue: this wave owns feature-group `group` for its 128-row slice
    int group = (bcol + wc) >> 6;          // 0..15
    int feat = (group << 4) | l15;         // 0..255
    float bc0 = b_conv[feat], bc1 = b_conv[FDIM + feat];
    float bc2 = b_conv[2 * FDIM + feat], bc3 = b_conv[3 * FDIM + feat];
    float bb0 = b[feat], bb1 = b[FDIM + feat];
    float bb2 = b[2 * FDIM + feat], bb3 = b[3 * FDIM + feat];
    float wci = w_c[feat], wcf = w_c[FDIM + feat], wco = w_c[2 * FDIM + feat];
    float wcl = Wcls[feat];
    float bias = (group == 0) ? bcls[0] : 0.f;

#pragma unroll
    for (int m = 0; m < 4; ++m) {
#pragma unroll
        for (int j = 0; j < 4; ++j) {
            int node = brow + wr + m * 16 + l4 * 4 + j;
            bool ok = node < M;
            int nidx = ok ? node : (M - 1);
            float cv = c[(size_t)nidx * FDIM + feat];
            float iv = sig(acc[m][0][j] + bc0 + wci * cv + bb0);
            float fv = sig(acc[m][1][j] + bc1 + wcf * cv + bb1);
            float tv = tanhf(acc[m][2][j] + bc2 + bb2);
            float cn = fv * cv + iv * tv;
            float ov = sig(acc[m][3][j] + bc3 + wco * cn + bb3);
            float hn = ov * tanhf(cn);
            if (ok) {
                out_h[(size_t)node * FDIM + feat] = hn;
                out_c[(size_t)node * FDIM + feat] = cn;
            }
            float pcls = fmaxf(hn, 0.f) * wcl;
#pragma unroll
            for (int s = 1; s < 16; s <<= 1) pcls += __shfl_xor(pcls, s);
            if (ok && l15 == 0) atomicAdd(&out_cls[node], pcls + bias);
        }
    }
}

// ---------------- launcher ----------------

extern "C" void kernel_launch(void* const* d_in, const int* in_sizes, int n_in,
                              void* d_out, int out_size, void* d_ws, size_t ws_size,
                              hipStream_t stream) {
    const float* x      = (const float*)d_in[0];
    const int*   eidx   = (const int*)d_in[1];
    const float* ew     = (const float*)d_in[2];
    const float* h      = (const float*)d_in[3];
    const float* c      = (const float*)d_in[4];
    const float* W      = (const float*)d_in[5];
    const float* theta  = (const float*)d_in[6];
    const float* b_conv = (const float*)d_in[7];
    const float* b      = (const float*)d_in[8];
    const float* w_c    = (const float*)d_in[9];
    const float* Wcls   = (const float*)d_in[10];
    const float* bcls   = (const float*)d_in[11];

    const int N = in_sizes[0] / FDIM;
    const int E = in_sizes[2];
    const int* src = eidx;
    const int* dst = eidx + E;
    const int mtiles = (N + 127) / 128;
    const int Mpad = mtiles * 128;

    char* ws = (char*)d_ws;
    size_t off = 0;
    auto alloc = [&](size_t bytes) -> void* {
        void* p = ws + off;
        off += (bytes + 255) & ~(size_t)255;
        return p;
    };
    unsigned short* A   = (unsigned short*)alloc((size_t)Mpad * KDIM * 2);
    unsigned short* Bt  = (unsigned short*)alloc((size_t)KDIM * KDIM * 2);
    float* deg          = (float*)alloc((size_t)N * 4);
    int*   cnt          = (int*)alloc((size_t)N * 4);
    int*   cur          = (int*)alloc((size_t)N * 4);
    int*   offs         = (int*)alloc((size_t)(N + 1) * 4);
    int*   part         = (int*)alloc(64 * 4);
    int2*  csr          = (int2*)alloc((size_t)E * 8);
    (void)ws_size; (void)n_in; (void)out_size;

    float* out_cls = (float*)d_out;
    float* out_h   = out_cls + N;
    float* out_c   = out_h + (size_t)N * FDIM;

    // zero deg/cnt/cur (consecutive allocs), classifier output, and A's pad rows
    size_t zbytes = (size_t)((char*)(cur + N) - (char*)deg);
    hipMemsetAsync(deg, 0, zbytes, stream);
    hipMemsetAsync(out_cls, 0, (size_t)N * 4, stream);
    if (Mpad > N)
        hipMemsetAsync(A + (size_t)N * KDIM, 0, (size_t)(Mpad - N) * KDIM * 2, stream);

    int nsb = (N + 1023) / 1024;  // <= 64
    int nbB = (KDIM * KDIM) / 256;            // 4096 packBt blocks
    int nbP = (N * 32 + 255) / 256;           // pre blocks
    k_pre<<<nbB + nbP, 256, 0, stream>>>(x, h, A, N, src, dst, ew, deg, cnt,
                                         W, theta, Bt, E, nbB);
    k_scan1<<<nsb, 1024, 0, stream>>>(cnt, offs, part, N);
    k_scan2<<<nsb, 1024, 0, stream>>>(offs, part, N);
    k_scatter<<<(E + 255) / 256, 256, 0, stream>>>(src, dst, ew, deg, offs, cur, csr, E);
    k_prop1<<<(N * 64 + 255) / 256, 256, 0, stream>>>(A, offs, csr, N);
    k_prop2<<<(N * 64 + 255) / 256, 256, 0, stream>>>(A, offs, csr, N);
    k_gemm<<<mtiles * 8, 256, 0, stream>>>(A, Bt, c, b_conv, b, w_c, Wcls, bcls,
                                           out_h, out_c, out_cls, N, mtiles);
}

// Round 11
// 184.903 us; speedup vs baseline: 1.1890x; 1.1890x over previous
//
#include <hip/hip_runtime.h>
#include <stdint.h>

#define FDIM 256
#define KDIM 1024   // 4*F : [x | h | Tx1 | L^Tx1]

typedef __attribute__((ext_vector_type(8))) short short8;
typedef __attribute__((ext_vector_type(4))) float floatx4;

#define GLOBAL_AS __attribute__((address_space(1)))
#define LDS_AS    __attribute__((address_space(3)))

static __device__ __forceinline__ unsigned short f2bf(float f) {
    unsigned int u = __float_as_uint(f);
    unsigned int r = (u + 0x7FFFu + ((u >> 16) & 1u)) >> 16;
    return (unsigned short)r;
}
static __device__ __forceinline__ float bf2f(unsigned short s) {
    return __uint_as_float(((unsigned int)s) << 16);
}
static __device__ __forceinline__ float sig(float x) {
    return 1.f / (1.f + __expf(-x));
}

// ---------------- fused prep: packBt + packA + degree/count ----------------
// Blocks [0, nbB): gate-interleaved packed B^T with Chebyshev fold:
//   out = x@W + h@(Th0-Th2) + Tx1@Th1 + (L^Tx1)@(2*Th2)
// Blocks [nbB, ...): bf16-pack x|h into A (32 thr/node, 16B stores) + edge atomics.
__global__ void k_pre(const float* __restrict__ x, const float* __restrict__ h,
                      unsigned short* __restrict__ A, int n,
                      const int* __restrict__ src, const int* __restrict__ dst,
                      const float* __restrict__ ew, float* deg, int* cnt,
                      const float* __restrict__ W, const float* __restrict__ theta,
                      unsigned short* __restrict__ Bt, int e, int nbB) {
    int bid = blockIdx.x;
    if (bid < nbB) {
        int t = bid * 256 + (int)threadIdx.x;       // over KDIM*KDIM
        int p = t >> 10, r = t & 1023;
        int group = p >> 6, gate = (p >> 4) & 3;
        int feat = (group << 4) | (p & 15);
        int kb = r >> 8, rr = r & 255;
        size_t g3 = (size_t)(gate * 3);
        float v;
        if (kb == 0)      v = W[((size_t)(gate * FDIM + rr)) * FDIM + feat];
        else if (kb == 1) v = theta[((g3 + 0) * FDIM + rr) * FDIM + feat]
                            - theta[((g3 + 2) * FDIM + rr) * FDIM + feat];
        else if (kb == 2) v = theta[((g3 + 1) * FDIM + rr) * FDIM + feat];
        else              v = 2.f * theta[((g3 + 2) * FDIM + rr) * FDIM + feat];
        Bt[t] = f2bf(v);
        return;
    }
    int t = (bid - nbB) * 256 + (int)threadIdx.x;
    if (t < e) {
        atomicAdd(&deg[src[t]], ew[t]);
        atomicAdd(&cnt[dst[t]], 1);
    }
    int node = t >> 5, q = t & 31;
    if (node >= n) return;
    const float* xp = x + (size_t)node * FDIM + q * 8;
    const float* hp = h + (size_t)node * FDIM + q * 8;
    floatx4 x0 = *(const floatx4*)xp, x1 = *(const floatx4*)(xp + 4);
    floatx4 h0 = *(const floatx4*)hp, h1 = *(const floatx4*)(hp + 4);
    short8 ox, oh;
#pragma unroll
    for (int k = 0; k < 4; ++k) {
        ox[k] = (short)f2bf(x0[k]); ox[4 + k] = (short)f2bf(x1[k]);
        oh[k] = (short)f2bf(h0[k]); oh[4 + k] = (short)f2bf(h1[k]);
    }
    *(short8*)(A + (size_t)node * KDIM + q * 8) = ox;
    *(short8*)(A + (size_t)node * KDIM + FDIM + q * 8) = oh;
}

// hierarchical scan, stage 1: per-1024-block inclusive scan -> offs[i+1], block total -> part[b]
__launch_bounds__(1024)
__global__ void k_scan1(const int* __restrict__ cnt, int* __restrict__ offs,
                        int* __restrict__ part, int n) {
    __shared__ int wsum[16];
    int b = blockIdx.x;
    int i = b * 1024 + (int)threadIdx.x;
    int lane = threadIdx.x & 63;
    int wid = threadIdx.x >> 6;
    int x = (i < n) ? cnt[i] : 0;
#pragma unroll
    for (int s = 1; s < 64; s <<= 1) {
        int t = __shfl_up(x, s);
        if (lane >= s) x += t;
    }
    if (lane == 63) wsum[wid] = x;
    __syncthreads();
    if (wid == 0) {
        int y = (lane < 16) ? wsum[lane] : 0;
#pragma unroll
        for (int s = 1; s < 16; s <<= 1) {
            int t = __shfl_up(y, s);
            if (lane >= s) y += t;
        }
        if (lane < 16) wsum[lane] = y;
    }
    __syncthreads();
    int wbase = (wid > 0) ? wsum[wid - 1] : 0;
    if (i < n) offs[i + 1] = wbase + x;
    if (threadIdx.x == 1023) part[b] = wsum[15];
}

// stage 2: add exclusive prefix of part[] to each block's region (nb <= 64)
__launch_bounds__(1024)
__global__ void k_scan2(int* __restrict__ offs, const int* __restrict__ part, int n) {
    __shared__ int sprefix;
    int b = blockIdx.x;
    if (threadIdx.x < 64) {
        int p = ((int)threadIdx.x < b) ? part[threadIdx.x] : 0;
#pragma unroll
        for (int s = 32; s; s >>= 1) p += __shfl_down(p, s);
        if (threadIdx.x == 0) sprefix = p;
    }
    __syncthreads();
    int i = b * 1024 + (int)threadIdx.x;
    if (i < n) offs[i + 1] += sprefix;
    if (b == 0 && threadIdx.x == 0) offs[0] = 0;
}

// scatter with inline rsqrt normalization; CSR record packed as int2{src, w}
__global__ void k_scatter(const int* __restrict__ src, const int* __restrict__ dst,
                          const float* __restrict__ ew, const float* __restrict__ deg,
                          const int* __restrict__ offs, int* cur,
                          int2* __restrict__ csr, int e) {
    int i = blockIdx.x * blockDim.x + threadIdx.x;
    if (i < e) {
        int s = src[i], d = dst[i];
        float ds_ = deg[s], dd = deg[d];
        float rs = ds_ > 0.f ? rsqrtf(fmaxf(ds_, 1e-12f)) : 0.f;
        float rd = dd > 0.f ? rsqrtf(fmaxf(dd, 1e-12f)) : 0.f;
        float wn = -rs * ew[i] * rd;
        int pos = offs[d] + atomicAdd(&cur[d], 1);
        csr[pos] = make_int2(s, __float_as_int(wn));
    }
}

// ---------------- sparse prop (CSR gather, wave per node, 2 half-waves x 4 unroll) ----------------

// Tx1 = prop(h): gather bf16 h from A[:,256:512], write bf16 to A[:,512:768]
__launch_bounds__(256)
__global__ void k_prop1(unsigned short* __restrict__ A, const int* __restrict__ offs,
                        const int2* __restrict__ csr, int n) {
    int wid = (blockIdx.x * blockDim.x + threadIdx.x) >> 6;
    int lane = threadIdx.x & 63;
    if (wid >= n) return;
    int half = lane >> 5, l = lane & 31;
    int beg = offs[wid], end = offs[wid + 1];
    float a[8] = {0.f, 0.f, 0.f, 0.f, 0.f, 0.f, 0.f, 0.f};
    int j = beg + half;
    for (; j + 6 < end; j += 8) {
        int2 e0 = csr[j], e1 = csr[j + 2], e2 = csr[j + 4], e3 = csr[j + 6];
        short8 v0 = *(const short8*)(A + (size_t)e0.x * KDIM + FDIM + l * 8);
        short8 v1 = *(const short8*)(A + (size_t)e1.x * KDIM + FDIM + l * 8);
        short8 v2 = *(const short8*)(A + (size_t)e2.x * KDIM + FDIM + l * 8);
        short8 v3 = *(const short8*)(A + (size_t)e3.x * KDIM + FDIM + l * 8);
        float w0 = __int_as_float(e0.y), w1 = __int_as_float(e1.y);
        float w2 = __int_as_float(e2.y), w3 = __int_as_float(e3.y);
#pragma unroll
        for (int k = 0; k < 8; ++k)
            a[k] += w0 * bf2f((unsigned short)v0[k]) + w1 * bf2f((unsigned short)v1[k])
                  + w2 * bf2f((unsigned short)v2[k]) + w3 * bf2f((unsigned short)v3[k]);
    }
    for (; j < end; j += 2) {
        int2 e0 = csr[j];
        float w0 = __int_as_float(e0.y);
        short8 v0 = *(const short8*)(A + (size_t)e0.x * KDIM + FDIM + l * 8);
#pragma unroll
        for (int k = 0; k < 8; ++k) a[k] += w0 * bf2f((unsigned short)v0[k]);
    }
#pragma unroll
    for (int k = 0; k < 8; ++k) a[k] += __shfl_xor(a[k], 32);
    if (half == 0) {
        short8 o;
#pragma unroll
        for (int k = 0; k < 8; ++k) o[k] = (short)f2bf(a[k]);
        *(short8*)(A + (size_t)wid * KDIM + 2 * FDIM + l * 8) = o;
    }
}

// T2' = L^(Tx1): pure gather of Tx1 (Cheb fold moved the -h / x2 into Bt)
__launch_bounds__(256)
__global__ void k_prop2(unsigned short* __restrict__ A, const int* __restrict__ offs,
                        const int2* __restrict__ csr, int n) {
    int wid = (blockIdx.x * blockDim.x + threadIdx.x) >> 6;
    int lane = threadIdx.x & 63;
    if (wid >= n) return;
    int half = lane >> 5, l = lane & 31;
    int beg = offs[wid], end = offs[wid + 1];
    float a[8] = {0.f, 0.f, 0.f, 0.f, 0.f, 0.f, 0.f, 0.f};
    int j = beg + half;
    for (; j + 6 < end; j += 8) {
        int2 e0 = csr[j], e1 = csr[j + 2], e2 = csr[j + 4], e3 = csr[j + 6];
        short8 v0 = *(const short8*)(A + (size_t)e0.x * KDIM + 2 * FDIM + l * 8);
        short8 v1 = *(const short8*)(A + (size_t)e1.x * KDIM + 2 * FDIM + l * 8);
        short8 v2 = *(const short8*)(A + (size_t)e2.x * KDIM + 2 * FDIM + l * 8);
        short8 v3 = *(const short8*)(A + (size_t)e3.x * KDIM + 2 * FDIM + l * 8);
        float w0 = __int_as_float(e0.y), w1 = __int_as_float(e1.y);
        float w2 = __int_as_float(e2.y), w3 = __int_as_float(e3.y);
#pragma unroll
        for (int k = 0; k < 8; ++k)
            a[k] += w0 * bf2f((unsigned short)v0[k]) + w1 * bf2f((unsigned short)v1[k])
                  + w2 * bf2f((unsigned short)v2[k]) + w3 * bf2f((unsigned short)v3[k]);
    }
    for (; j < end; j += 2) {
        int2 e0 = csr[j];
        float w0 = __int_as_float(e0.y);
        short8 v0 = *(const short8*)(A + (size_t)e0.x * KDIM + 2 * FDIM + l * 8);
#pragma unroll
        for (int k = 0; k < 8; ++k) a[k] += w0 * bf2f((unsigned short)v0[k]);
    }
#pragma unroll
    for (int k = 0; k < 8; ++k) a[k] += __shfl_xor(a[k], 32);
    if (half == 0) {
        short8 o;
#pragma unroll
        for (int k = 0; k < 8; ++k) o[k] = (short)f2bf(a[k]);
        *(short8*)(A + (size_t)wid * KDIM + 3 * FDIM + l * 8) = o;
    }
}

// ---------------- GEMM + fused LSTM epilogue (R3/R8-proven structure) ----------------
// BK=64, XOR-swizzled LDS, SINGLE-buffer, 2 barriers/iter — triple-confirmed optimum.
// Explored & regressed: fine vmcnt+sched_barrier (R4), L2-direct B (R5),
// (256,5) occupancy force (R7: 48-VGPR spills), dbuf+single-barrier (R10:
// __syncthreads drains vmcnt(0) INCLUDING the prefetch -> no overlap, half
// occupancy). Do not re-attempt schedule surgery at HIP level.
// __launch_bounds__(256,3): 60 VGPR, no spills. A padded -> no row clamp.

__launch_bounds__(256, 3)
__global__ void k_gemm(const unsigned short* __restrict__ A, const unsigned short* __restrict__ Bt,
                       const float* __restrict__ c, const float* __restrict__ b_conv,
                       const float* __restrict__ b, const float* __restrict__ w_c,
                       const float* __restrict__ Wcls, const float* __restrict__ bcls,
                       float* __restrict__ out_h, float* __restrict__ out_c,
                       float* __restrict__ out_cls, int M, int mtiles) {
    __shared__ unsigned short sA[128 * 64];
    __shared__ unsigned short sB[128 * 64];
    int tid = threadIdx.x;
    int lane = tid & 63;
    int w = tid >> 6;
    // XCD-aware swizzle: 8 consecutive nt-blocks (one A panel) land on one XCD chunk
    int nb = mtiles * 8;
    int bid = blockIdx.x;
    int wg = (bid & 7) * (nb >> 3) + (bid >> 3);
    int mt = wg >> 3;
    int nt = wg & 7;
    int brow = mt * 128, bcol = nt * 128;
    int wr = (w >> 1) * 64, wc = (w & 1) * 64;
    int l15 = lane & 15, l4 = lane >> 4;

    floatx4 acc[4][4];
#pragma unroll
    for (int m = 0; m < 4; ++m)
#pragma unroll
        for (int g = 0; g < 4; ++g)
            acc[m][g] = (floatx4){0.f, 0.f, 0.f, 0.f};

    for (int kt = 0; kt < 16; ++kt) {
        int k0 = kt * 64;
#pragma unroll
        for (int p = 0; p < 4; ++p) {
            int cch = tid + p * 256;            // 0..1023 chunks of 16B
            int row = cch >> 3, cslot = cch & 7;
            int csrc = cslot ^ (row & 7);       // inverse-swizzled source chunk
            const unsigned short* g = A + (size_t)(brow + row) * KDIM + k0 + csrc * 8;
            __builtin_amdgcn_global_load_lds((const GLOBAL_AS void*)g,
                                             (LDS_AS void*)(sA + cch * 8), 16, 0, 0);
        }
#pragma unroll
        for (int p = 0; p < 4; ++p) {
            int cch = tid + p * 256;
            int row = cch >> 3, cslot = cch & 7;
            int csrc = cslot ^ (row & 7);
            const unsigned short* g = Bt + (size_t)(bcol + row) * KDIM + k0 + csrc * 8;
            __builtin_amdgcn_global_load_lds((const GLOBAL_AS void*)g,
                                             (LDS_AS void*)(sB + cch * 8), 16, 0, 0);
        }
        __syncthreads();

#pragma unroll
        for (int ks = 0; ks < 2; ++ks) {
            short8 af[4], bfr[4];
#pragma unroll
            for (int m = 0; m < 4; ++m) {
                int ra = wr + m * 16 + l15;
                af[m] = *(const short8*)(sA + ra * 64 + ((ks * 4 + l4) ^ (ra & 7)) * 8);
            }
#pragma unroll
            for (int g = 0; g < 4; ++g) {
                int rb = wc + g * 16 + l15;
                bfr[g] = *(const short8*)(sB + rb * 64 + ((ks * 4 + l4) ^ (rb & 7)) * 8);
            }
#pragma unroll
            for (int m = 0; m < 4; ++m)
#pragma unroll
                for (int g = 0; g < 4; ++g)
                    acc[m][g] = __builtin_amdgcn_mfma_f32_16x16x32_bf16(af[m], bfr[g], acc[m][g], 0, 0, 0);
        }
        __syncthreads();
    }

    // fused epilogue: this wave owns feature-group `group` for its 128-row slice
    int group = (bcol + wc) >> 6;          // 0..15
    int feat = (group << 4) | l15;         // 0..255
    float bc0 = b_conv[feat], bc1 = b_conv[FDIM + feat];
    float bc2 = b_conv[2 * FDIM + feat], bc3 = b_conv[3 * FDIM + feat];
    float bb0 = b[feat], bb1 = b[FDIM + feat];
    float bb2 = b[2 * FDIM + feat], bb3 = b[3 * FDIM + feat];
    float wci = w_c[feat], wcf = w_c[FDIM + feat], wco = w_c[2 * FDIM + feat];
    float wcl = Wcls[feat];
    float bias = (group == 0) ? bcls[0] : 0.f;

#pragma unroll
    for (int m = 0; m < 4; ++m) {
#pragma unroll
        for (int j = 0; j < 4; ++j) {
            int node = brow + wr + m * 16 + l4 * 4 + j;
            bool ok = node < M;
            int nidx = ok ? node : (M - 1);
            float cv = c[(size_t)nidx * FDIM + feat];
            float iv = sig(acc[m][0][j] + bc0 + wci * cv + bb0);
            float fv = sig(acc[m][1][j] + bc1 + wcf * cv + bb1);
            float tv = tanhf(acc[m][2][j] + bc2 + bb2);
            float cn = fv * cv + iv * tv;
            float ov = sig(acc[m][3][j] + bc3 + wco * cn + bb3);
            float hn = ov * tanhf(cn);
            if (ok) {
                out_h[(size_t)node * FDIM + feat] = hn;
                out_c[(size_t)node * FDIM + feat] = cn;
            }
            float pcls = fmaxf(hn, 0.f) * wcl;
#pragma unroll
            for (int s = 1; s < 16; s <<= 1) pcls += __shfl_xor(pcls, s);
            if (ok && l15 == 0) atomicAdd(&out_cls[node], pcls + bias);
        }
    }
}

// ---------------- launcher ----------------

extern "C" void kernel_launch(void* const* d_in, const int* in_sizes, int n_in,
                              void* d_out, int out_size, void* d_ws, size_t ws_size,
                              hipStream_t stream) {
    const float* x      = (const float*)d_in[0];
    const int*   eidx   = (const int*)d_in[1];
    const float* ew     = (const float*)d_in[2];
    const float* h      = (const float*)d_in[3];
    const float* c      = (const float*)d_in[4];
    const float* W      = (const float*)d_in[5];
    const float* theta  = (const float*)d_in[6];
    const float* b_conv = (const float*)d_in[7];
    const float* b      = (const float*)d_in[8];
    const float* w_c    = (const float*)d_in[9];
    const float* Wcls   = (const float*)d_in[10];
    const float* bcls   = (const float*)d_in[11];

    const int N = in_sizes[0] / FDIM;
    const int E = in_sizes[2];
    const int* src = eidx;
    const int* dst = eidx + E;
    const int mtiles = (N + 127) / 128;
    const int Mpad = mtiles * 128;

    char* ws = (char*)d_ws;
    size_t off = 0;
    auto alloc = [&](size_t bytes) -> void* {
        void* p = ws + off;
        off += (bytes + 255) & ~(size_t)255;
        return p;
    };
    unsigned short* A   = (unsigned short*)alloc((size_t)Mpad * KDIM * 2);
    unsigned short* Bt  = (unsigned short*)alloc((size_t)KDIM * KDIM * 2);
    float* deg          = (float*)alloc((size_t)N * 4);
    int*   cnt          = (int*)alloc((size_t)N * 4);
    int*   cur          = (int*)alloc((size_t)N * 4);
    int*   offs         = (int*)alloc((size_t)(N + 1) * 4);
    int*   part         = (int*)alloc(64 * 4);
    int2*  csr          = (int2*)alloc((size_t)E * 8);
    (void)ws_size; (void)n_in; (void)out_size;

    float* out_cls = (float*)d_out;
    float* out_h   = out_cls + N;
    float* out_c   = out_h + (size_t)N * FDIM;

    // zero deg/cnt/cur (consecutive allocs), classifier output, and A's pad rows
    size_t zbytes = (size_t)((char*)(cur + N) - (char*)deg);
    hipMemsetAsync(deg, 0, zbytes, stream);
    hipMemsetAsync(out_cls, 0, (size_t)N * 4, stream);
    if (Mpad > N)
        hipMemsetAsync(A + (size_t)N * KDIM, 0, (size_t)(Mpad - N) * KDIM * 2, stream);

    int nsb = (N + 1023) / 1024;  // <= 64
    int nbB = (KDIM * KDIM) / 256;            // 4096 packBt blocks
    int nbP = (N * 32 + 255) / 256;           // pre blocks
    k_pre<<<nbB + nbP, 256, 0, stream>>>(x, h, A, N, src, dst, ew, deg, cnt,
                                         W, theta, Bt, E, nbB);
    k_scan1<<<nsb, 1024, 0, stream>>>(cnt, offs, part, N);
    k_scan2<<<nsb, 1024, 0, stream>>>(offs, part, N);
    k_scatter<<<(E + 255) / 256, 256, 0, stream>>>(src, dst, ew, deg, offs, cur, csr, E);
    k_prop1<<<(N * 64 + 255) / 256, 256, 0, stream>>>(A, offs, csr, N);
    k_prop2<<<(N * 64 + 255) / 256, 256, 0, stream>>>(A, offs, csr, N);
    k_gemm<<<mtiles * 8, 256, 0, stream>>>(A, Bt, c, b_conv, b, w_c, Wcls, bcls,
                                           out_h, out_c, out_cls, N, mtiles);
}